// Round 13
// baseline (2066.147 us; speedup 1.0000x reference)
//
#include <hip/hip_runtime.h>
#include <hip/hip_bf16.h>
#include <hip/hip_fp16.h>

typedef short bf16x8 __attribute__((ext_vector_type(8)));
typedef float f32x4 __attribute__((ext_vector_type(4)));
typedef unsigned short u16x4 __attribute__((ext_vector_type(4)));
typedef unsigned short u16x8 __attribute__((ext_vector_type(8)));
typedef unsigned int uint32;

#define MFMA_B16(a,b,c) __builtin_amdgcn_mfma_f32_16x16x32_bf16(a,b,c,0,0,0)

// ---------------- geometry ----------------
#define NS   1024
#define TLEN 128
#define DD   343
#define HH   150
#define GG   600
#define KX   352    // XBF row width (global)
#define XR   360    // xs LDS row width (720B)
#define HR   168    // hs LDS row width (336B)
#define KXP  44
#define NP   640    // gate-major padded dim: n' = gate*160 + j, j<160
#define NG2  640    // XG2 row width (gate-major)
#define NCHUNK 2816 // 64 rows x 44 16B-chunks per TB=8 stage

// ---------------- ws layout (bytes) ----------------
#define OFF_WXP  0u
#define OFF_WHP  901120u
#define OFF_B1   1310720u
#define OFF_W2B  1315840u
#define OFF_W2I  1725440u
#define OFF_SE   3184640u
#define OFF_XG2  4413440u
#define OFF_H2O  9656320u
#define OFF_XBF  10885120u
#define NEED_BF  103159808ull

// prep section boundaries (element counts)
#define PE0 450560
#define PE1 655360
#define PE2 656640
#define PE3 861440
#define PE4 1226240

__device__ __forceinline__ float rcp_fast(float x) { return __builtin_amdgcn_rcpf(x); }
__device__ __forceinline__ float sigm(float x) { return rcp_fast(1.f + __expf(-x)); }
__device__ __forceinline__ float tanh_fast(float x) { return 1.f - 2.f * rcp_fast(__expf(2.f * x) + 1.f); }

__device__ __forceinline__ void bar_lds() {
  asm volatile("s_waitcnt lgkmcnt(0)" ::: "memory");
  __builtin_amdgcn_s_barrier();
  asm volatile("" ::: "memory");
}
__device__ __forceinline__ void bar_full() {
  asm volatile("s_waitcnt vmcnt(0) lgkmcnt(0)" ::: "memory");
  __builtin_amdgcn_s_barrier();
  asm volatile("" ::: "memory");
}

__device__ __forceinline__ unsigned short f2bu(float v) {
  __hip_bfloat16 b = __float2bfloat16(v);
  return __builtin_bit_cast(unsigned short, b);
}

// ---------------- prep: pack weights gate-major (n' = g*160 + j) ----------------
__global__ __launch_bounds__(256) void prep_kernel(
    const float* __restrict__ wif1, const float* __restrict__ whf1,
    const float* __restrict__ bif1, const float* __restrict__ bhf1,
    const float* __restrict__ wib1, const float* __restrict__ whb1,
    const float* __restrict__ bib1, const float* __restrict__ bhb1,
    const float* __restrict__ wif2, const float* __restrict__ wib2,
    const float* __restrict__ whf2, const float* __restrict__ whb2,
    __hip_bfloat16* __restrict__ WXp, __hip_bfloat16* __restrict__ WHp,
    float* __restrict__ B1, __hip_bfloat16* __restrict__ W2B, float* __restrict__ W2I)
{
  int i = blockIdx.x * 256 + threadIdx.x;
  if (i < PE0) {
    int d = i / 225280; int r = i - d * 225280;
    int p = r / 5120;   int r2 = r - p * 5120;
    int n2 = r2 >> 3;   int jj = r2 & 7;
    int k = p * 8 + jj;
    int g = n2 / 160, j = n2 - g * 160;
    const float* w = d ? wib1 : wif1;
    float v = (j < HH && k < DD) ? w[(g * HH + j) * DD + k] : 0.f;
    WXp[i] = __float2bfloat16(v);
  } else if (i < PE1) {
    int ii = i - PE0;
    int d = ii / 102400; int r = ii - d * 102400;
    int p = r / 5120;    int r2 = r - p * 5120;
    int n2 = r2 >> 3;    int jj = r2 & 7;
    int k = p * 8 + jj;
    int g = n2 / 160, j = n2 - g * 160;
    const float* w = d ? whb1 : whf1;
    float v = (j < HH && k < HH) ? w[(g * HH + j) * HH + k] : 0.f;
    WHp[ii] = __float2bfloat16(v);
  } else if (i < PE2) {
    int ii = i - PE1;
    int d = ii / NP; int n2 = ii - d * NP;
    int g = n2 / 160, j = n2 - g * 160;
    float v = 0.f;
    if (j < HH) {
      int n = g * HH + j;
      v = d ? (bib1[n] + bhb1[n]) : (bif1[n] + bhf1[n]);
    }
    B1[ii] = v;
  } else if (i < PE3) {
    int ii = i - PE2;
    int d = ii / 102400; int r = ii - d * 102400;
    int n2 = r / 160;    int k = r - n2 * 160;
    int g = n2 / 160, j = n2 - g * 160;
    const float* w = d ? whb2 : whf2;
    float v = (j < HH && k < HH) ? w[(g * HH + j) * HH + k] : 0.f;
    W2B[ii] = __float2bfloat16(v);
  } else if (i < PE4) {
    int ii = i - PE3;
    int d = ii / 182400; int r = ii - d * 182400;
    int k = r / 608;     int n = r - k * 608;
    const float* w = d ? wib2 : wif2;
    float v = (n < GG) ? w[n * 300 + k] : 0.f;
    W2I[ii] = v;
  }
}

// ---------------- x -> bf16 padded [S][T][352] ----------------
__global__ __launch_bounds__(256) void xcvt_kernel(
    const float* __restrict__ x, __hip_bfloat16* __restrict__ XBF)
{
  const int total4 = NS * TLEN * (KX / 4);
  for (int idx = blockIdx.x * 256 + threadIdx.x; idx < total4; idx += gridDim.x * 256) {
    int row = idx / 88;
    int c4 = (idx - row * 88) * 4;
    const float* src = x + (size_t)row * DD + c4;
    float v0 = 0.f, v1 = 0.f, v2 = 0.f, v3 = 0.f;
    if (c4 + 3 < DD) {
      v0 = __builtin_nontemporal_load(src);
      v1 = __builtin_nontemporal_load(src + 1);
      v2 = __builtin_nontemporal_load(src + 2);
      v3 = __builtin_nontemporal_load(src + 3);
    } else {
      if (c4 < DD)     v0 = src[0];
      if (c4 + 1 < DD) v1 = src[1];
      if (c4 + 2 < DD) v2 = src[2];
    }
    u16x4 o;
    o.x = f2bu(v0); o.y = f2bu(v1); o.z = f2bu(v2); o.w = f2bu(v3);
    u16x4* dst = (u16x4*)((unsigned short*)XBF + (size_t)row * KX + c4);
    __builtin_nontemporal_store(o, dst);
  }
}

// ---------------- layer-1: gate-major, in-register cell, TB=8, NT reg-staging ----------------
// x is staged via __builtin_nontemporal_load (real NT CPol bit, unlike
// global_load_lds aux) into regs right after phase A; ds_write deferred to just
// before the g-loop barrier (T14 split: HBM latency hides under phase B).
// NT keeps the streaming x from evicting the L2-resident 450KB weight slice
// (round-12 PMC: 1.15GB of weight L2-miss traffic = the lstm1 bound).
#define XS_SZ   46080u                    // bf16 [4 tiles][16][360]
#define HS_OFF  (2u * XS_SZ)              // bf16 [16][168] = 5376
#define L1_SMEM (HS_OFF + 5376u)          // 97536 -> 1 block/CU

__device__ __forceinline__ void chunk_addr(int e, int t0, int dir, int s0,
                                           int& row16, int& col16, size_t& goff)
{
  row16 = e / 44; col16 = e - row16 * 44;
  int p = row16 >> 4, rr = row16 & 15;
  int t = t0 + 2 * p + (rr >> 3);
  int s = s0 + (rr & 7);
  int tt = dir ? (127 - t) : t;
  goff = ((size_t)s * TLEN + tt) * KX + col16 * 8;
}

__device__ __forceinline__ void stage_load(u16x8* xreg, const __hip_bfloat16* __restrict__ XBF,
                                           int t0, int dir, int s0, int tid)
{
  #pragma unroll
  for (int i = 0; i < 5; ++i) {
    int e = tid + i * 640;
    if (e < NCHUNK) {
      int row16, col16; size_t goff;
      chunk_addr(e, t0, dir, s0, row16, col16, goff);
      xreg[i] = __builtin_nontemporal_load((const u16x8*)(XBF + goff));
    }
  }
}

__device__ __forceinline__ void stage_write(char* xsd, const u16x8* xreg, int tid)
{
  #pragma unroll
  for (int i = 0; i < 5; ++i) {
    int e = tid + i * 640;
    if (e < NCHUNK) {
      int row16 = e / 44, col16 = e - row16 * 44;
      *(u16x8*)(xsd + row16 * 720 + col16 * 16) = xreg[i];
    }
  }
}

template<bool BF>
__global__ __launch_bounds__(640)
void lstm1_kernel(
    const float* __restrict__ x, const __hip_bfloat16* __restrict__ XBF,
    const __hip_bfloat16* __restrict__ WXp, const __hip_bfloat16* __restrict__ WHp,
    const float* __restrict__ B1, float* __restrict__ SE)
{
  extern __shared__ char smem[];
  char* xs0 = smem;
  char* xs1 = smem + XS_SZ;
  __hip_bfloat16* hs = (__hip_bfloat16*)(smem + HS_OFF);

  const int tid = threadIdx.x;
  const int lane = tid & 63;
  const int wv = tid >> 6;            // 0..9 = j-tile
  const int dir = blockIdx.x & 1;
  const int s0 = (blockIdx.x >> 1) * 8;
  const int c16 = lane & 15;
  const int kgrp = lane >> 4;
  const int j = wv * 16 + c16;        // 0..159

  for (int e = tid; e < 16 * HR; e += 640) hs[e] = __float2bfloat16(0.f);

  float bias[4];
  #pragma unroll
  for (int g4 = 0; g4 < 4; ++g4) {
    bias[g4] = B1[dir * NP + g4 * 160 + j];
    asm volatile("" : "+v"(bias[g4]));
  }

  const __hip_bfloat16* WXd = WXp + (size_t)dir * KXP * NP * 8;
  const __hip_bfloat16* WHd = WHp + (size_t)dir * 20 * NP * 8;

  bf16x8 whr[5][4];
  #pragma unroll
  for (int kh = 0; kh < 5; ++kh)
    #pragma unroll
    for (int g4 = 0; g4 < 4; ++g4) {
      whr[kh][g4] = *reinterpret_cast<const bf16x8*>(
          WHd + ((size_t)(kh * 4 + kgrp) * NP + g4 * 160 + j) * 8);
      asm volatile("" : "+v"(whr[kh][g4]));
    }

  float creg[4] = {0.f, 0.f, 0.f, 0.f};
  float mxr[4] = {-3e38f, -3e38f, -3e38f, -3e38f};

  u16x8 xreg[5];
  // prologue: stage tile 0 into xs0
  if constexpr (BF) {
    stage_load(xreg, XBF, 0, dir, s0, tid);
    asm volatile("s_waitcnt vmcnt(0)" ::: "memory");
    stage_write(xs0, xreg, tid);
  } else {
    for (int e = tid; e < 4 * 16 * XR; e += 640) {
      int row16 = e / XR, col = e - row16 * XR;
      int p = row16 >> 4, rr = row16 & 15;
      int t = 2 * p + (rr >> 3);
      int s = s0 + (rr & 7);
      int tt = dir ? (127 - t) : t;
      float v = (col < DD) ? x[((size_t)s * TLEN + tt) * DD + col] : 0.f;
      ((__hip_bfloat16*)xs0)[e] = __float2bfloat16(v);
    }
  }
  bar_full();

  for (int g = 0; g < 16; ++g) {
    char* xsc = (g & 1) ? xs1 : xs0;
    char* xsn = (g & 1) ? xs0 : xs1;
    const __hip_bfloat16* xsb = (const __hip_bfloat16*)xsc;

    f32x4 acc[4][4];
    #pragma unroll
    for (int p = 0; p < 4; ++p)
      #pragma unroll
      for (int g4 = 0; g4 < 4; ++g4) acc[p][g4] = (f32x4){0.f, 0.f, 0.f, 0.f};

    // ---- phase A: x-projection for 8 steps (4 row-paired tiles) ----
    for (int kk = 0; kk < 11; ++kk) {
      bf16x8 a[4], b[4];
      #pragma unroll
      for (int p = 0; p < 4; ++p)
        a[p] = *reinterpret_cast<const bf16x8*>(xsb + (p * 16 + c16) * XR + kk * 32 + kgrp * 8);
      #pragma unroll
      for (int g4 = 0; g4 < 4; ++g4)
        b[g4] = *reinterpret_cast<const bf16x8*>(
            WXd + ((size_t)(kk * 4 + kgrp) * NP + g4 * 160 + j) * 8);
      #pragma unroll
      for (int p = 0; p < 4; ++p)
        #pragma unroll
        for (int g4 = 0; g4 < 4; ++g4)
          acc[p][g4] = MFMA_B16(a[p], b[g4], acc[p][g4]);
    }

    // issue next tile's NT loads now; latency hides under phase B
    if (g < 15) {
      if constexpr (BF) {
        stage_load(xreg, XBF, (g + 1) * 8, dir, s0, tid);
      } else {
        for (int e = tid; e < 4 * 16 * XR; e += 640) {
          int row16 = e / XR, col = e - row16 * XR;
          int p = row16 >> 4, rr = row16 & 15;
          int t = (g + 1) * 8 + 2 * p + (rr >> 3);
          int s = s0 + (rr & 7);
          int tt = dir ? (127 - t) : t;
          float v = (col < DD) ? x[((size_t)s * TLEN + tt) * DD + col] : 0.f;
          ((__hip_bfloat16*)xsn)[e] = __float2bfloat16(v);
        }
      }
    }

    // ---- phase B: 4 pairs = 8 recurrent steps ----
    #pragma unroll
    for (int p = 0; p < 4; ++p) {
      // MFMA1: rows 0-7 += h_prev_odd * Wh  (rows 8-15 see zeros)
      #pragma unroll
      for (int kh = 0; kh < 5; ++kh) {
        bf16x8 ah = *reinterpret_cast<const bf16x8*>(hs + c16 * HR + kh * 32 + kgrp * 8);
        #pragma unroll
        for (int g4 = 0; g4 < 4; ++g4)
          acc[p][g4] = MFMA_B16(ah, whr[kh][g4], acc[p][g4]);
      }
      {
        const bool act = (kgrp < 2);
        #pragma unroll
        for (int r = 0; r < 4; ++r) {
          float iv = sigm(acc[p][0][r] + bias[0]);
          float fv = sigm(acc[p][1][r] + bias[1]);
          float gv = tanh_fast(acc[p][2][r] + bias[2]);
          float ov = sigm(acc[p][3][r] + bias[3]);
          float cin = __shfl_xor(creg[r], 32);
          float cn = fv * cin + iv * gv;
          float h = ov * tanh_fast(cn);
          creg[r] = act ? cn : creg[r];
          mxr[r] = act ? fmaxf(mxr[r], h) : mxr[r];
          if (act) hs[(8 + kgrp * 4 + r) * HR + j] = __float2bfloat16(h);
        }
      }
      bar_lds();
      // MFMA2: rows 8-15 += h_even * Wh (rows 0-7 dead)
      #pragma unroll
      for (int kh = 0; kh < 5; ++kh) {
        bf16x8 ah = *reinterpret_cast<const bf16x8*>(hs + c16 * HR + kh * 32 + kgrp * 8);
        #pragma unroll
        for (int g4 = 0; g4 < 4; ++g4)
          acc[p][g4] = MFMA_B16(ah, whr[kh][g4], acc[p][g4]);
      }
      {
        const bool act = (kgrp >= 2);
        #pragma unroll
        for (int r = 0; r < 4; ++r) {
          float iv = sigm(acc[p][0][r] + bias[0]);
          float fv = sigm(acc[p][1][r] + bias[1]);
          float gv = tanh_fast(acc[p][2][r] + bias[2]);
          float ov = sigm(acc[p][3][r] + bias[3]);
          float cin = __shfl_xor(creg[r], 32);
          float cn = fv * cin + iv * gv;
          float h = ov * tanh_fast(cn);
          creg[r] = act ? cn : creg[r];
          mxr[r] = act ? fmaxf(mxr[r], h) : mxr[r];
          if (act) {
            int s = (kgrp - 2) * 4 + r;
            hs[s * HR + j] = __float2bfloat16(h);
            hs[(8 + s) * HR + j] = __float2bfloat16(0.f);
          }
        }
      }
      if (p == 3) {
        if constexpr (BF) {
          if (g < 15) {
            asm volatile("s_waitcnt vmcnt(0)" ::: "memory");
            stage_write(xsn, xreg, tid);
          }
        }
        bar_full();
      } else {
        bar_lds();
      }
    }
  }

  // SE: merge even/odd running max via shfl, write by kgrp<2 lanes
  #pragma unroll
  for (int r = 0; r < 4; ++r) {
    float m = fmaxf(mxr[r], __shfl_xor(mxr[r], 32));
    if (kgrp < 2 && j < HH)
      SE[(size_t)(s0 + kgrp * 4 + r) * 300 + dir * HH + j] = m;
  }
}

// ---------------- layer-2 input projection (gate-major output, zero pad) ----------------
__global__ __launch_bounds__(256, 1) void xg2_kernel(
    const float* __restrict__ SE, const float* __restrict__ W2I,
    const float* __restrict__ bif2, const float* __restrict__ bhf2,
    const float* __restrict__ bib2, const float* __restrict__ bhb2,
    float* __restrict__ XG2)
{
  __shared__ float se[32 * 304];
  const int d = blockIdx.x >> 5, st = blockIdx.x & 31, sb = st * 32;
  const int tid = threadIdx.x;
  for (int e = tid; e < 32 * 300; e += 256) {
    int si = e / 300, k = e - si * 300;
    se[si * 304 + k] = SE[(size_t)(sb + si) * 300 + k];
  }
  __syncthreads();
  for (int pass = 0; pass < 3; ++pass) {
    int n = pass * 256 + tid;
    if (n < GG) {
      int n2 = (n / 150) * 160 + (n % 150);
      float bias = d ? (bib2[n] + bhb2[n]) : (bif2[n] + bhf2[n]);
      float acc[32];
      #pragma unroll
      for (int si = 0; si < 32; ++si) acc[si] = bias;
      const float* wcol = W2I + (size_t)d * 300 * 608 + n;
      for (int k = 0; k < 300; ++k) {
        float wvv = wcol[(size_t)k * 608];
        #pragma unroll
        for (int si = 0; si < 32; ++si) acc[si] += wvv * se[si * 304 + k];
      }
      #pragma unroll
      for (int si = 0; si < 32; ++si)
        XG2[((size_t)d * NS + sb + si) * NG2 + n2] = acc[si];
    }
  }
  for (int e = tid; e < 32 * 40; e += 256) {
    int si = e / 40, q = e - si * 40;
    int g = q / 10, jp = 150 + (q - g * 10);
    XG2[((size_t)d * NS + sb + si) * NG2 + g * 160 + jp] = 0.f;
  }
}

// ---------------- layer-2 recurrence: gate-major MFMA, depth-1 chains ----------------
__global__ __launch_bounds__(640) void lstm2_kernel(
    const __hip_bfloat16* __restrict__ W2B, const float* __restrict__ XG2,
    float* __restrict__ H2O)
{
  const int dir = blockIdx.x;
  const int tid = threadIdx.x;
  const int lane = tid & 63;
  const int wv = tid >> 6;        // 0..9 = j-tile
  const int c16 = lane & 15;
  const int kg = lane >> 4;
  const int j = wv * 16 + c16;    // 0..159
  __shared__ __align__(16) __hip_bfloat16 hbuf[2][160];

  const f32x4 ZERO4 = {0.f, 0.f, 0.f, 0.f};

  const __hip_bfloat16* Wd = W2B + (size_t)dir * NP * 160;
  bf16x8 wf[5][4];
  #pragma unroll
  for (int kt = 0; kt < 5; ++kt)
    #pragma unroll
    for (int g4 = 0; g4 < 4; ++g4) {
      wf[kt][g4] = *reinterpret_cast<const bf16x8*>(
          Wd + (size_t)(g4 * 160 + j) * 160 + kt * 32 + kg * 8);
      asm volatile("" : "+v"(wf[kt][g4]));
    }

  if (tid < 160) hbuf[0][tid] = __float2bfloat16(0.f);
  __syncthreads();

  float creg = 0.f;
  const float* xg = XG2 + (size_t)dir * NS * NG2;
  float xv[4];
  {
    int ss0 = dir ? 1023 : 0;
    #pragma unroll
    for (int g4 = 0; g4 < 4; ++g4) xv[g4] = xg[(size_t)ss0 * NG2 + g4 * 160 + j];
  }

  for (int step = 0; step < 1024; ++step) {
    const int ss = dir ? (1023 - step) : step;
    float xn[4] = {0.f, 0.f, 0.f, 0.f};
    if (step < 1023) {
      int ss2 = dir ? (1022 - step) : (step + 1);
      #pragma unroll
      for (int g4 = 0; g4 < 4; ++g4) xn[g4] = xg[(size_t)ss2 * NG2 + g4 * 160 + j];
    }
    const int cur = step & 1;
    bf16x8 hf[5];
    #pragma unroll
    for (int kt = 0; kt < 5; ++kt)
      hf[kt] = *reinterpret_cast<const bf16x8*>(&hbuf[cur][kt * 32 + kg * 8]);
    // depth-1 MFMA chains: 20 independent MFMAs, reduce on VALU
    float y[4];
    #pragma unroll
    for (int g4 = 0; g4 < 4; ++g4) {
      f32x4 c0 = MFMA_B16(hf[0], wf[0][g4], ZERO4);
      f32x4 c1 = MFMA_B16(hf[1], wf[1][g4], ZERO4);
      f32x4 c2 = MFMA_B16(hf[2], wf[2][g4], ZERO4);
      f32x4 c3 = MFMA_B16(hf[3], wf[3][g4], ZERO4);
      f32x4 c4 = MFMA_B16(hf[4], wf[4][g4], ZERO4);
      y[g4] = ((c0[0] + c1[0]) + (c2[0] + c3[0])) + c4[0];
    }
    float iv = sigm(y[0] + xv[0]);
    float fv = sigm(y[1] + xv[1]);
    float gv = tanh_fast(y[2] + xv[2]);
    float ov = sigm(y[3] + xv[3]);
    creg = fv * creg + iv * gv;
    float nh = ov * tanh_fast(creg);
    if (kg == 0) {
      hbuf[cur ^ 1][j] = __float2bfloat16(nh);
      if (j < HH) H2O[(size_t)ss * 300 + dir * HH + j] = nh;
    }
    bar_lds();
    #pragma unroll
    for (int g4 = 0; g4 < 4; ++g4) xv[g4] = xn[g4];
  }
}

// ---------------- head ----------------
__global__ __launch_bounds__(256, 1) void head_kernel(
    const float* __restrict__ H2O, const float* __restrict__ w_out,
    const float* __restrict__ b_out, float* __restrict__ out)
{
  int s = blockIdx.x * 256 + threadIdx.x;
  if (s >= NS) return;
  float acc[7];
  #pragma unroll
  for (int c = 0; c < 7; ++c) acc[c] = b_out[c];
  const float* hrow = H2O + (size_t)s * 300;
  for (int k = 0; k < 300; ++k) {
    float hv = hrow[k];
    #pragma unroll
    for (int c = 0; c < 7; ++c) acc[c] += hv * w_out[c * 300 + k];
  }
  float m = acc[0];
  #pragma unroll
  for (int c = 1; c < 7; ++c) m = fmaxf(m, acc[c]);
  float sum = 0.f;
  #pragma unroll
  for (int c = 0; c < 7; ++c) sum += __expf(acc[c] - m);
  float lse = m + __logf(sum);
  #pragma unroll
  for (int c = 0; c < 7; ++c) out[s * 7 + c] = acc[c] - lse;
}

extern "C" void kernel_launch(void* const* d_in, const int* in_sizes, int n_in,
                              void* d_out, int out_size, void* d_ws, size_t ws_size,
                              hipStream_t stream) {
  const float* x      = (const float*)d_in[0];
  const float* wif1   = (const float*)d_in[1];
  const float* whf1   = (const float*)d_in[2];
  const float* bif1   = (const float*)d_in[3];
  const float* bhf1   = (const float*)d_in[4];
  const float* wib1   = (const float*)d_in[5];
  const float* whb1   = (const float*)d_in[6];
  const float* bib1   = (const float*)d_in[7];
  const float* bhb1   = (const float*)d_in[8];
  const float* wif2   = (const float*)d_in[9];
  const float* whf2   = (const float*)d_in[10];
  const float* bif2   = (const float*)d_in[11];
  const float* bhf2   = (const float*)d_in[12];
  const float* wib2   = (const float*)d_in[13];
  const float* whb2   = (const float*)d_in[14];
  const float* bib2   = (const float*)d_in[15];
  const float* bhb2   = (const float*)d_in[16];
  const float* w_out  = (const float*)d_in[17];
  const float* b_out  = (const float*)d_in[18];

  char* ws = (char*)d_ws;
  __hip_bfloat16* WXp = (__hip_bfloat16*)(ws + OFF_WXP);
  __hip_bfloat16* WHp = (__hip_bfloat16*)(ws + OFF_WHP);
  float*    B1  = (float*)(ws + OFF_B1);
  __hip_bfloat16* W2B = (__hip_bfloat16*)(ws + OFF_W2B);
  float*    W2I = (float*)(ws + OFF_W2I);
  float*    SE  = (float*)(ws + OFF_SE);
  float*    XG2 = (float*)(ws + OFF_XG2);
  float*    H2O = (float*)(ws + OFF_H2O);
  __hip_bfloat16* XBF = (__hip_bfloat16*)(ws + OFF_XBF);

  const bool useBF = (ws_size >= NEED_BF);

  prep_kernel<<<(PE4 + 255) / 256, 256, 0, stream>>>(
      wif1, whf1, bif1, bhf1, wib1, whb1, bib1, bhb1,
      wif2, wib2, whf2, whb2, WXp, WHp, B1, W2B, W2I);

  if (useBF)
    xcvt_kernel<<<4096, 256, 0, stream>>>(x, XBF);

  (void)hipFuncSetAttribute((const void*)(lstm1_kernel<true>),
                            hipFuncAttributeMaxDynamicSharedMemorySize, L1_SMEM);
  (void)hipFuncSetAttribute((const void*)(lstm1_kernel<false>),
                            hipFuncAttributeMaxDynamicSharedMemorySize, L1_SMEM);

  if (useBF)
    lstm1_kernel<true><<<256, 640, L1_SMEM, stream>>>(x, XBF, WXp, WHp, B1, SE);
  else
    lstm1_kernel<false><<<256, 640, L1_SMEM, stream>>>(x, XBF, WXp, WHp, B1, SE);

  xg2_kernel<<<64, 256, 0, stream>>>(SE, W2I, bif2, bhf2, bib2, bhb2, XG2);

  lstm2_kernel<<<2, 640, 0, stream>>>(W2B, XG2, H2O);

  head_kernel<<<4, 256, 0, stream>>>(H2O, w_out, b_out, (float*)d_out);
}

// Round 14
// 1609.925 us; speedup vs baseline: 1.2834x; 1.2834x over previous
//
#include <hip/hip_runtime.h>
#include <hip/hip_bf16.h>
#include <hip/hip_fp16.h>

typedef short bf16x8 __attribute__((ext_vector_type(8)));
typedef float f32x4 __attribute__((ext_vector_type(4)));
typedef unsigned short u16x4 __attribute__((ext_vector_type(4)));
typedef unsigned int uint32;

#define MFMA_B16(a,b,c) __builtin_amdgcn_mfma_f32_16x16x32_bf16(a,b,c,0,0,0)

// ---------------- geometry ----------------
#define NS   1024
#define TLEN 128
#define DD   343
#define HH   150
#define GG   600
#define KX   352    // XBF row width (global)
#define XR   360    // LDS row width for x tiles (720B = 45x16B odd)
#define HR   168    // hs LDS row width
#define KXP  44
#define NP   640    // gate-major padded dim: n' = gate*160 + j
#define NG2  640

// ---------------- ws layout (bytes) ----------------
#define OFF_WXP  0u
#define OFF_WHP  901120u
#define OFF_B1   1310720u
#define OFF_W2B  1315840u
#define OFF_W2I  1725440u
#define OFF_SE   3184640u
#define OFF_XG2  4413440u
#define OFF_H2O  9656320u
#define OFF_XBF  10885120u          // bf16 [1024][128][352] = 92274688
#define NEED_BF  103159808ull
#define OFF_XG1  103159808ull       // f32 [2][1024][128][640] = 671088640
#define NEED_SPLIT 774248448ull

// prep section boundaries (element counts)
#define PE0 450560
#define PE1 655360
#define PE2 656640
#define PE3 861440
#define PE4 1226240

__device__ __forceinline__ float rcp_fast(float x) { return __builtin_amdgcn_rcpf(x); }
__device__ __forceinline__ float sigm(float x) { return rcp_fast(1.f + __expf(-x)); }
__device__ __forceinline__ float tanh_fast(float x) { return 1.f - 2.f * rcp_fast(__expf(2.f * x) + 1.f); }

typedef __attribute__((address_space(1))) const void GASV;
typedef __attribute__((address_space(3))) void LASV;
__device__ __forceinline__ void gload_lds16(const void* g, void* l) {
  __builtin_amdgcn_global_load_lds((GASV*)g, (LASV*)l, 16, 0, 0);
}

__device__ __forceinline__ void bar_lds() {
  asm volatile("s_waitcnt lgkmcnt(0)" ::: "memory");
  __builtin_amdgcn_s_barrier();
  asm volatile("" ::: "memory");
}
__device__ __forceinline__ void bar_full() {
  asm volatile("s_waitcnt vmcnt(0) lgkmcnt(0)" ::: "memory");
  __builtin_amdgcn_s_barrier();
  asm volatile("" ::: "memory");
}

__device__ __forceinline__ unsigned short f2bu(float v) {
  __hip_bfloat16 b = __float2bfloat16(v);
  return __builtin_bit_cast(unsigned short, b);
}

// ---------------- prep: pack weights gate-major (n' = g*160 + j) ----------------
__global__ __launch_bounds__(256) void prep_kernel(
    const float* __restrict__ wif1, const float* __restrict__ whf1,
    const float* __restrict__ bif1, const float* __restrict__ bhf1,
    const float* __restrict__ wib1, const float* __restrict__ whb1,
    const float* __restrict__ bib1, const float* __restrict__ bhb1,
    const float* __restrict__ wif2, const float* __restrict__ wib2,
    const float* __restrict__ whf2, const float* __restrict__ whb2,
    __hip_bfloat16* __restrict__ WXp, __hip_bfloat16* __restrict__ WHp,
    float* __restrict__ B1, __hip_bfloat16* __restrict__ W2B, float* __restrict__ W2I)
{
  int i = blockIdx.x * 256 + threadIdx.x;
  if (i < PE0) {
    int d = i / 225280; int r = i - d * 225280;
    int p = r / 5120;   int r2 = r - p * 5120;
    int n2 = r2 >> 3;   int jj = r2 & 7;
    int k = p * 8 + jj;
    int g = n2 / 160, j = n2 - g * 160;
    const float* w = d ? wib1 : wif1;
    float v = (j < HH && k < DD) ? w[(g * HH + j) * DD + k] : 0.f;
    WXp[i] = __float2bfloat16(v);
  } else if (i < PE1) {
    int ii = i - PE0;
    int d = ii / 102400; int r = ii - d * 102400;
    int p = r / 5120;    int r2 = r - p * 5120;
    int n2 = r2 >> 3;    int jj = r2 & 7;
    int k = p * 8 + jj;
    int g = n2 / 160, j = n2 - g * 160;
    const float* w = d ? whb1 : whf1;
    float v = (j < HH && k < HH) ? w[(g * HH + j) * HH + k] : 0.f;
    WHp[ii] = __float2bfloat16(v);
  } else if (i < PE2) {
    int ii = i - PE1;
    int d = ii / NP; int n2 = ii - d * NP;
    int g = n2 / 160, j = n2 - g * 160;
    float v = 0.f;
    if (j < HH) {
      int n = g * HH + j;
      v = d ? (bib1[n] + bhb1[n]) : (bif1[n] + bhf1[n]);
    }
    B1[ii] = v;
  } else if (i < PE3) {
    int ii = i - PE2;
    int d = ii / 102400; int r = ii - d * 102400;
    int n2 = r / 160;    int k = r - n2 * 160;
    int g = n2 / 160, j = n2 - g * 160;
    const float* w = d ? whb2 : whf2;
    float v = (j < HH && k < HH) ? w[(g * HH + j) * HH + k] : 0.f;
    W2B[ii] = __float2bfloat16(v);
  } else if (i < PE4) {
    int ii = i - PE3;
    int d = ii / 182400; int r = ii - d * 182400;
    int k = r / 608;     int n = r - k * 608;
    const float* w = d ? wib2 : wif2;
    float v = (n < GG) ? w[n * 300 + k] : 0.f;
    W2I[ii] = v;
  }
}

// ---------------- x -> bf16 padded [S][T][352] ----------------
__global__ __launch_bounds__(256) void xcvt_kernel(
    const float* __restrict__ x, __hip_bfloat16* __restrict__ XBF)
{
  const int total4 = NS * TLEN * (KX / 4);
  for (int idx = blockIdx.x * 256 + threadIdx.x; idx < total4; idx += gridDim.x * 256) {
    int row = idx / 88;
    int c4 = (idx - row * 88) * 4;
    const float* src = x + (size_t)row * DD + c4;
    float v0 = 0.f, v1 = 0.f, v2 = 0.f, v3 = 0.f;
    if (c4 + 3 < DD) {
      v0 = __builtin_nontemporal_load(src);
      v1 = __builtin_nontemporal_load(src + 1);
      v2 = __builtin_nontemporal_load(src + 2);
      v3 = __builtin_nontemporal_load(src + 3);
    } else {
      if (c4 < DD)     v0 = src[0];
      if (c4 + 1 < DD) v1 = src[1];
      if (c4 + 2 < DD) v2 = src[2];
    }
    u16x4 o;
    o.x = f2bu(v0); o.y = f2bu(v1); o.z = f2bu(v2); o.w = f2bu(v3);
    u16x4* dst = (u16x4*)((unsigned short*)XBF + (size_t)row * KX + c4);
    __builtin_nontemporal_store(o, dst);
  }
}

// ---------------- layer-1 input GEMM: XG1 = XBF @ WXp^T + B1 ----------------
// M=131072 (s*128+t), N=1280 (2 dirs x 640 gate-major). Grid 10240 = 1024 Mtiles
// x 10 Ntiles(128). 512 thr / 8 waves (2Mx4N); wave tile 64x32; acc[4][2].
// A staged once (whole K=352) into 90KB LDS via gload_lds, B streams from L2.
#define GA_SMEM (128u * 720u)   // 92160

__global__ __launch_bounds__(512) void xg1_gemm(
    const __hip_bfloat16* __restrict__ XBF, const __hip_bfloat16* __restrict__ WXp,
    const float* __restrict__ B1, float* __restrict__ XG1)
{
  extern __shared__ char smem[];
  __hip_bfloat16* xsA = (__hip_bfloat16*)smem;

  const int bid = blockIdx.x;
  const int mt = bid / 10;
  const int ntile = bid - mt * 10;
  const int dir = ntile / 5;
  const int nb = (ntile - dir * 5) * 128;
  const int m0 = mt * 128;

  const int tid = threadIdx.x;
  const int lane = tid & 63;
  const int wv = tid >> 6;          // 0..7
  const int wr = wv >> 2;           // 0..1
  const int wc = wv & 3;            // 0..3
  const int arow = lane & 15;
  const int kgrp = lane >> 4;

  // stage A: 128 rows x 704B, 16 rows per wave, 44 lanes each
  #pragma unroll
  for (int i = 0; i < 16; ++i) {
    int rid = wv * 16 + i;
    if (lane < 44) {
      const __hip_bfloat16* gp = XBF + (size_t)(m0 + rid) * KX + lane * 8;
      gload_lds16((const void*)gp, (void*)(smem + rid * 720));
    }
  }
  bar_full();

  const __hip_bfloat16* WXd = WXp + (size_t)dir * KXP * NP * 8;

  f32x4 acc[4][2];
  #pragma unroll
  for (int mi = 0; mi < 4; ++mi)
    #pragma unroll
    for (int ni = 0; ni < 2; ++ni) acc[mi][ni] = (f32x4){0.f, 0.f, 0.f, 0.f};

  for (int kk = 0; kk < 11; ++kk) {
    bf16x8 a[4], b[2];
    #pragma unroll
    for (int mi = 0; mi < 4; ++mi)
      a[mi] = *reinterpret_cast<const bf16x8*>(
          xsA + (wr * 64 + mi * 16 + arow) * XR + kk * 32 + kgrp * 8);
    #pragma unroll
    for (int ni = 0; ni < 2; ++ni)
      b[ni] = *reinterpret_cast<const bf16x8*>(
          WXd + ((size_t)(kk * 4 + kgrp) * NP + nb + wc * 32 + ni * 16 + arow) * 8);
    #pragma unroll
    for (int mi = 0; mi < 4; ++mi)
      #pragma unroll
      for (int ni = 0; ni < 2; ++ni)
        acc[mi][ni] = MFMA_B16(a[mi], b[ni], acc[mi][ni]);
  }

  // epilogue: add bias, write f32 [dir][s][t][640]
  float bias[2];
  #pragma unroll
  for (int ni = 0; ni < 2; ++ni)
    bias[ni] = B1[dir * NP + nb + wc * 32 + ni * 16 + arow];

  float* outd = XG1 + (size_t)dir * NS * TLEN * NG2;
  #pragma unroll
  for (int mi = 0; mi < 4; ++mi) {
    #pragma unroll
    for (int r = 0; r < 4; ++r) {
      int m = m0 + wr * 64 + mi * 16 + kgrp * 4 + r;
      int s = m >> 7, t = m & 127;
      float* row = outd + ((size_t)s * TLEN + t) * NG2;
      #pragma unroll
      for (int ni = 0; ni < 2; ++ni)
        row[nb + wc * 32 + ni * 16 + arow] = acc[mi][ni][r] + bias[ni];
    }
  }
}

// ---------------- layer-1 recurrence (no weight streaming, no spill) ----------------
// 256 blocks (128 groups x 2 dirs), 640 thr / 10 waves; wave wv = j-tile.
// Per pair-step: C-init from XG1 (prefetched one pair ahead), 2x(5x4) MFMA with
// W_hh in regs, in-register cell, c-state via shfl_xor(32). Regs ~145 < 170.
__global__ __launch_bounds__(640) void lstm1_rec(
    const float* __restrict__ XG1, const __hip_bfloat16* __restrict__ WHp,
    float* __restrict__ SE)
{
  __shared__ __hip_bfloat16 hs[16 * HR];

  const int tid = threadIdx.x;
  const int lane = tid & 63;
  const int wv = tid >> 6;
  const int dir = blockIdx.x & 1;
  const int s0 = (blockIdx.x >> 1) * 8;
  const int c16 = lane & 15;
  const int kgrp = lane >> 4;
  const int j = wv * 16 + c16;

  for (int e = tid; e < 16 * HR; e += 640) hs[e] = __float2bfloat16(0.f);

  const __hip_bfloat16* WHd = WHp + (size_t)dir * 20 * NP * 8;
  bf16x8 whr[5][4];
  #pragma unroll
  for (int kh = 0; kh < 5; ++kh)
    #pragma unroll
    for (int g4 = 0; g4 < 4; ++g4) {
      whr[kh][g4] = *reinterpret_cast<const bf16x8*>(
          WHd + ((size_t)(kh * 4 + kgrp) * NP + g4 * 160 + j) * 8);
      asm volatile("" : "+v"(whr[kh][g4]));
    }

  float creg[4] = {0.f, 0.f, 0.f, 0.f};
  float mxr[4] = {-3e38f, -3e38f, -3e38f, -3e38f};

  const float* xgd = XG1 + (size_t)dir * NS * TLEN * NG2;
  const int sentb = s0 + (kgrp & 1) * 4;   // this thread's 4 sentences base
  const int par = kgrp >> 1;               // 0 = even step rows, 1 = odd

  float xq[16], xqN[16];
  // prologue: load pair 0 C-init
  #pragma unroll
  for (int g4 = 0; g4 < 4; ++g4)
    #pragma unroll
    for (int r = 0; r < 4; ++r) {
      int tl = par;                        // pair 0: t = 0+par
      int tt = dir ? (127 - tl) : tl;
      xq[g4 * 4 + r] = xgd[((size_t)(sentb + r) * TLEN + tt) * NG2 + g4 * 160 + j];
    }
  __syncthreads();

  for (int p = 0; p < 64; ++p) {
    f32x4 acc[4];
    #pragma unroll
    for (int g4 = 0; g4 < 4; ++g4) {
      acc[g4][0] = xq[g4 * 4 + 0]; acc[g4][1] = xq[g4 * 4 + 1];
      acc[g4][2] = xq[g4 * 4 + 2]; acc[g4][3] = xq[g4 * 4 + 3];
    }
    if (p < 63) {
      #pragma unroll
      for (int g4 = 0; g4 < 4; ++g4)
        #pragma unroll
        for (int r = 0; r < 4; ++r) {
          int tl = 2 * (p + 1) + par;
          int tt = dir ? (127 - tl) : tl;
          xqN[g4 * 4 + r] = xgd[((size_t)(sentb + r) * TLEN + tt) * NG2 + g4 * 160 + j];
        }
    }
    // MFMA1: rows 0-7 += h_prev_odd * Wh (rows 8-15 see zeros)
    #pragma unroll
    for (int kh = 0; kh < 5; ++kh) {
      bf16x8 ah = *reinterpret_cast<const bf16x8*>(hs + c16 * HR + kh * 32 + kgrp * 8);
      #pragma unroll
      for (int g4 = 0; g4 < 4; ++g4)
        acc[g4] = MFMA_B16(ah, whr[kh][g4], acc[g4]);
    }
    {
      const bool act = (kgrp < 2);
      #pragma unroll
      for (int r = 0; r < 4; ++r) {
        float iv = sigm(acc[0][r]);
        float fv = sigm(acc[1][r]);
        float gv = tanh_fast(acc[2][r]);
        float ov = sigm(acc[3][r]);
        float cin = __shfl_xor(creg[r], 32);
        float cn = fv * cin + iv * gv;
        float h = ov * tanh_fast(cn);
        creg[r] = act ? cn : creg[r];
        mxr[r] = act ? fmaxf(mxr[r], h) : mxr[r];
        if (act) hs[(8 + kgrp * 4 + r) * HR + j] = __float2bfloat16(h);
      }
    }
    bar_lds();
    // MFMA2: rows 8-15 += h_even * Wh
    #pragma unroll
    for (int kh = 0; kh < 5; ++kh) {
      bf16x8 ah = *reinterpret_cast<const bf16x8*>(hs + c16 * HR + kh * 32 + kgrp * 8);
      #pragma unroll
      for (int g4 = 0; g4 < 4; ++g4)
        acc[g4] = MFMA_B16(ah, whr[kh][g4], acc[g4]);
    }
    {
      const bool act = (kgrp >= 2);
      #pragma unroll
      for (int r = 0; r < 4; ++r) {
        float iv = sigm(acc[0][r]);
        float fv = sigm(acc[1][r]);
        float gv = tanh_fast(acc[2][r]);
        float ov = sigm(acc[3][r]);
        float cin = __shfl_xor(creg[r], 32);
        float cn = fv * cin + iv * gv;
        float h = ov * tanh_fast(cn);
        creg[r] = act ? cn : creg[r];
        mxr[r] = act ? fmaxf(mxr[r], h) : mxr[r];
        if (act) {
          int s = (kgrp - 2) * 4 + r;
          hs[s * HR + j] = __float2bfloat16(h);
          hs[(8 + s) * HR + j] = __float2bfloat16(0.f);
        }
      }
    }
    bar_lds();
    #pragma unroll
    for (int q = 0; q < 16; ++q) xq[q] = xqN[q];
  }

  #pragma unroll
  for (int r = 0; r < 4; ++r) {
    float m = fmaxf(mxr[r], __shfl_xor(mxr[r], 32));
    if (kgrp < 2 && j < HH)
      SE[(size_t)(s0 + kgrp * 4 + r) * 300 + dir * HH + j] = m;
  }
}

// ---------------- FALLBACK layer-1 (round-12 fused version) ----------------
#define XS_SZ   46080u
#define HS_OFF  (2u * XS_SZ)
#define L1_SMEM (HS_OFF + 5376u)

template<bool BF>
__device__ __forceinline__ void stage_x(char* xsd, const float* __restrict__ x,
                                        const __hip_bfloat16* __restrict__ XBF,
                                        int t0, int dir, int s0, int tid, int lane, int wv)
{
  if constexpr (BF) {
    #pragma unroll
    for (int i = 0; i < 7; ++i) {
      int rid = wv + i * 10;
      if (rid < 64 && lane < 44) {
        int p = rid >> 4, rr = rid & 15;
        int t = t0 + 2 * p + (rr >> 3);
        int s = s0 + (rr & 7);
        int tt = dir ? (127 - t) : t;
        const __hip_bfloat16* gp = XBF + ((size_t)s * TLEN + tt) * KX + lane * 8;
        gload_lds16((const void*)gp, (void*)(xsd + rid * 720));
      }
    }
  } else {
    for (int e = tid; e < 4 * 16 * XR; e += 640) {
      int row16 = e / XR;
      int col = e - row16 * XR;
      int p = row16 >> 4, rr = row16 & 15;
      int t = t0 + 2 * p + (rr >> 3);
      int s = s0 + (rr & 7);
      int tt = dir ? (127 - t) : t;
      float v = (col < DD) ? x[((size_t)s * TLEN + tt) * DD + col] : 0.f;
      ((__hip_bfloat16*)xsd)[e] = __float2bfloat16(v);
    }
  }
}

template<bool BF>
__global__ __launch_bounds__(640)
void lstm1_kernel(
    const float* __restrict__ x, const __hip_bfloat16* __restrict__ XBF,
    const __hip_bfloat16* __restrict__ WXp, const __hip_bfloat16* __restrict__ WHp,
    const float* __restrict__ B1, float* __restrict__ SE)
{
  extern __shared__ char smem[];
  char* xs0 = smem;
  char* xs1 = smem + XS_SZ;
  __hip_bfloat16* hs = (__hip_bfloat16*)(smem + HS_OFF);

  const int tid = threadIdx.x;
  const int lane = tid & 63;
  const int wv = tid >> 6;
  const int dir = blockIdx.x & 1;
  const int s0 = (blockIdx.x >> 1) * 8;
  const int c16 = lane & 15;
  const int kgrp = lane >> 4;
  const int j = wv * 16 + c16;

  for (int e = tid; e < 16 * HR; e += 640) hs[e] = __float2bfloat16(0.f);

  float bias[4];
  #pragma unroll
  for (int g4 = 0; g4 < 4; ++g4) {
    bias[g4] = B1[dir * NP + g4 * 160 + j];
    asm volatile("" : "+v"(bias[g4]));
  }

  const __hip_bfloat16* WXd = WXp + (size_t)dir * KXP * NP * 8;
  const __hip_bfloat16* WHd = WHp + (size_t)dir * 20 * NP * 8;

  bf16x8 whr[5][4];
  #pragma unroll
  for (int kh = 0; kh < 5; ++kh)
    #pragma unroll
    for (int g4 = 0; g4 < 4; ++g4) {
      whr[kh][g4] = *reinterpret_cast<const bf16x8*>(
          WHd + ((size_t)(kh * 4 + kgrp) * NP + g4 * 160 + j) * 8);
      asm volatile("" : "+v"(whr[kh][g4]));
    }

  float creg[4] = {0.f, 0.f, 0.f, 0.f};
  float mxr[4] = {-3e38f, -3e38f, -3e38f, -3e38f};

  stage_x<BF>(xs0, x, XBF, 0, dir, s0, tid, lane, wv);
  bar_full();

  for (int g = 0; g < 16; ++g) {
    char* xsc = (g & 1) ? xs1 : xs0;
    char* xsn = (g & 1) ? xs0 : xs1;
    const __hip_bfloat16* xsb = (const __hip_bfloat16*)xsc;

    f32x4 acc[4][4];
    #pragma unroll
    for (int p = 0; p < 4; ++p)
      #pragma unroll
      for (int g4 = 0; g4 < 4; ++g4) acc[p][g4] = (f32x4){0.f, 0.f, 0.f, 0.f};

    for (int kk = 0; kk < 11; ++kk) {
      bf16x8 a[4], b[4];
      #pragma unroll
      for (int p = 0; p < 4; ++p)
        a[p] = *reinterpret_cast<const bf16x8*>(xsb + (p * 16 + c16) * XR + kk * 32 + kgrp * 8);
      #pragma unroll
      for (int g4 = 0; g4 < 4; ++g4)
        b[g4] = *reinterpret_cast<const bf16x8*>(
            WXd + ((size_t)(kk * 4 + kgrp) * NP + g4 * 160 + j) * 8);
      #pragma unroll
      for (int p = 0; p < 4; ++p)
        #pragma unroll
        for (int g4 = 0; g4 < 4; ++g4)
          acc[p][g4] = MFMA_B16(a[p], b[g4], acc[p][g4]);
    }

    if (g < 15)
      stage_x<BF>(xsn, x, XBF, (g + 1) * 8, dir, s0, tid, lane, wv);

    #pragma unroll
    for (int p = 0; p < 4; ++p) {
      #pragma unroll
      for (int kh = 0; kh < 5; ++kh) {
        bf16x8 ah = *reinterpret_cast<const bf16x8*>(hs + c16 * HR + kh * 32 + kgrp * 8);
        #pragma unroll
        for (int g4 = 0; g4 < 4; ++g4)
          acc[p][g4] = MFMA_B16(ah, whr[kh][g4], acc[p][g4]);
      }
      {
        const bool act = (kgrp < 2);
        #pragma unroll
        for (int r = 0; r < 4; ++r) {
          float iv = sigm(acc[p][0][r] + bias[0]);
          float fv = sigm(acc[p][1][r] + bias[1]);
          float gv = tanh_fast(acc[p][2][r] + bias[2]);
          float ov = sigm(acc[p][3][r] + bias[3]);
          float cin = __shfl_xor(creg[r], 32);
          float cn = fv * cin + iv * gv;
          float h = ov * tanh_fast(cn);
          creg[r] = act ? cn : creg[r];
          mxr[r] = act ? fmaxf(mxr[r], h) : mxr[r];
          if (act) hs[(8 + kgrp * 4 + r) * HR + j] = __float2bfloat16(h);
        }
      }
      bar_lds();
      #pragma unroll
      for (int kh = 0; kh < 5; ++kh) {
        bf16x8 ah = *reinterpret_cast<const bf16x8*>(hs + c16 * HR + kh * 32 + kgrp * 8);
        #pragma unroll
        for (int g4 = 0; g4 < 4; ++g4)
          acc[p][g4] = MFMA_B16(ah, whr[kh][g4], acc[p][g4]);
      }
      {
        const bool act = (kgrp >= 2);
        #pragma unroll
        for (int r = 0; r < 4; ++r) {
          float iv = sigm(acc[p][0][r] + bias[0]);
          float fv = sigm(acc[p][1][r] + bias[1]);
          float gv = tanh_fast(acc[p][2][r] + bias[2]);
          float ov = sigm(acc[p][3][r] + bias[3]);
          float cin = __shfl_xor(creg[r], 32);
          float cn = fv * cin + iv * gv;
          float h = ov * tanh_fast(cn);
          creg[r] = act ? cn : creg[r];
          mxr[r] = act ? fmaxf(mxr[r], h) : mxr[r];
          if (act) {
            int s = (kgrp - 2) * 4 + r;
            hs[s * HR + j] = __float2bfloat16(h);
            hs[(8 + s) * HR + j] = __float2bfloat16(0.f);
          }
        }
      }
      if (p == 3) bar_full(); else bar_lds();
    }
  }

  #pragma unroll
  for (int r = 0; r < 4; ++r) {
    float m = fmaxf(mxr[r], __shfl_xor(mxr[r], 32));
    if (kgrp < 2 && j < HH)
      SE[(size_t)(s0 + kgrp * 4 + r) * 300 + dir * HH + j] = m;
  }
}

// ---------------- layer-2 input projection (gate-major output, zero pad) ----------------
__global__ __launch_bounds__(256, 1) void xg2_kernel(
    const float* __restrict__ SE, const float* __restrict__ W2I,
    const float* __restrict__ bif2, const float* __restrict__ bhf2,
    const float* __restrict__ bib2, const float* __restrict__ bhb2,
    float* __restrict__ XG2)
{
  __shared__ float se[32 * 304];
  const int d = blockIdx.x >> 5, st = blockIdx.x & 31, sb = st * 32;
  const int tid = threadIdx.x;
  for (int e = tid; e < 32 * 300; e += 256) {
    int si = e / 300, k = e - si * 300;
    se[si * 304 + k] = SE[(size_t)(sb + si) * 300 + k];
  }
  __syncthreads();
  for (int pass = 0; pass < 3; ++pass) {
    int n = pass * 256 + tid;
    if (n < GG) {
      int n2 = (n / 150) * 160 + (n % 150);
      float bias = d ? (bib2[n] + bhb2[n]) : (bif2[n] + bhf2[n]);
      float acc[32];
      #pragma unroll
      for (int si = 0; si < 32; ++si) acc[si] = bias;
      const float* wcol = W2I + (size_t)d * 300 * 608 + n;
      for (int k = 0; k < 300; ++k) {
        float wvv = wcol[(size_t)k * 608];
        #pragma unroll
        for (int si = 0; si < 32; ++si) acc[si] += wvv * se[si * 304 + k];
      }
      #pragma unroll
      for (int si = 0; si < 32; ++si)
        XG2[((size_t)d * NS + sb + si) * NG2 + n2] = acc[si];
    }
  }
  for (int e = tid; e < 32 * 40; e += 256) {
    int si = e / 40, q = e - si * 40;
    int g = q / 10, jp = 150 + (q - g * 10);
    XG2[((size_t)d * NS + sb + si) * NG2 + g * 160 + jp] = 0.f;
  }
}

// ---------------- layer-2 recurrence: round-12 MFMA + depth-2 xg prefetch ----------------
__global__ __launch_bounds__(640) void lstm2_kernel(
    const __hip_bfloat16* __restrict__ W2B, const float* __restrict__ XG2,
    float* __restrict__ H2O)
{
  const int dir = blockIdx.x;
  const int tid = threadIdx.x;
  const int lane = tid & 63;
  const int wv = tid >> 6;
  const int c16 = lane & 15;
  const int kg = lane >> 4;
  const int j = wv * 16 + c16;
  __shared__ __align__(16) __hip_bfloat16 hbuf[2][160];

  const f32x4 ZERO4 = {0.f, 0.f, 0.f, 0.f};

  const __hip_bfloat16* Wd = W2B + (size_t)dir * NP * 160;
  bf16x8 wf[5][4];
  #pragma unroll
  for (int kt = 0; kt < 5; ++kt)
    #pragma unroll
    for (int g4 = 0; g4 < 4; ++g4) {
      wf[kt][g4] = *reinterpret_cast<const bf16x8*>(
          Wd + (size_t)(g4 * 160 + j) * 160 + kt * 32 + kg * 8);
      asm volatile("" : "+v"(wf[kt][g4]));
    }

  if (tid < 160) hbuf[0][tid] = __float2bfloat16(0.f);
  __syncthreads();

  float creg = 0.f;
  const float* xg = XG2 + (size_t)dir * NS * NG2;

  float xqC[8], xqN[8];
  // prologue: group 0 (steps 0,1)
  #pragma unroll
  for (int q = 0; q < 2; ++q)
    #pragma unroll
    for (int g4 = 0; g4 < 4; ++g4) {
      int sl = q;
      int ss2 = dir ? (1023 - sl) : sl;
      xqC[q * 4 + g4] = xg[(size_t)ss2 * NG2 + g4 * 160 + j];
    }

  for (int grp = 0; grp < 512; ++grp) {
    // prefetch next group's xg (2 steps ahead: covers HBM cold-miss latency)
    #pragma unroll
    for (int q = 0; q < 2; ++q)
      #pragma unroll
      for (int g4 = 0; g4 < 4; ++g4) {
        int sl = grp * 2 + 2 + q;
        if (sl < 1024) {
          int ss2 = dir ? (1023 - sl) : sl;
          xqN[q * 4 + g4] = xg[(size_t)ss2 * NG2 + g4 * 160 + j];
        } else {
          xqN[q * 4 + g4] = 0.f;
        }
      }
    #pragma unroll
    for (int q = 0; q < 2; ++q) {
      const int step = grp * 2 + q;
      const int ss = dir ? (1023 - step) : step;
      bf16x8 hf[5];
      #pragma unroll
      for (int kt = 0; kt < 5; ++kt)
        hf[kt] = *reinterpret_cast<const bf16x8*>(&hbuf[q][kt * 32 + kg * 8]);
      f32x4 aA[4], aB[4];
      #pragma unroll
      for (int g4 = 0; g4 < 4; ++g4) {
        aA[g4] = MFMA_B16(hf[0], wf[0][g4], ZERO4);
        aB[g4] = MFMA_B16(hf[1], wf[1][g4], ZERO4);
      }
      #pragma unroll
      for (int g4 = 0; g4 < 4; ++g4) {
        aA[g4] = MFMA_B16(hf[2], wf[2][g4], aA[g4]);
        aB[g4] = MFMA_B16(hf[3], wf[3][g4], aB[g4]);
        aA[g4] = MFMA_B16(hf[4], wf[4][g4], aA[g4]);
      }
      float iv = sigm(aA[0][0] + aB[0][0] + xqC[q * 4 + 0]);
      float fv = sigm(aA[1][0] + aB[1][0] + xqC[q * 4 + 1]);
      float gv = tanh_fast(aA[2][0] + aB[2][0] + xqC[q * 4 + 2]);
      float ov = sigm(aA[3][0] + aB[3][0] + xqC[q * 4 + 3]);
      creg = fv * creg + iv * gv;
      float nh = ov * tanh_fast(creg);
      if (kg == 0) {
        hbuf[q ^ 1][j] = __float2bfloat16(nh);
        if (j < HH) H2O[(size_t)ss * 300 + dir * HH + j] = nh;
      }
      bar_lds();
    }
    #pragma unroll
    for (int q = 0; q < 8; ++q) xqC[q] = xqN[q];
  }
}

// ---------------- head ----------------
__global__ __launch_bounds__(256, 1) void head_kernel(
    const float* __restrict__ H2O, const float* __restrict__ w_out,
    const float* __restrict__ b_out, float* __restrict__ out)
{
  int s = blockIdx.x * 256 + threadIdx.x;
  if (s >= NS) return;
  float acc[7];
  #pragma unroll
  for (int c = 0; c < 7; ++c) acc[c] = b_out[c];
  const float* hrow = H2O + (size_t)s * 300;
  for (int k = 0; k < 300; ++k) {
    float hv = hrow[k];
    #pragma unroll
    for (int c = 0; c < 7; ++c) acc[c] += hv * w_out[c * 300 + k];
  }
  float m = acc[0];
  #pragma unroll
  for (int c = 1; c < 7; ++c) m = fmaxf(m, acc[c]);
  float sum = 0.f;
  #pragma unroll
  for (int c = 0; c < 7; ++c) sum += __expf(acc[c] - m);
  float lse = m + __logf(sum);
  #pragma unroll
  for (int c = 0; c < 7; ++c) out[s * 7 + c] = acc[c] - lse;
}

extern "C" void kernel_launch(void* const* d_in, const int* in_sizes, int n_in,
                              void* d_out, int out_size, void* d_ws, size_t ws_size,
                              hipStream_t stream) {
  const float* x      = (const float*)d_in[0];
  const float* wif1   = (const float*)d_in[1];
  const float* whf1   = (const float*)d_in[2];
  const float* bif1   = (const float*)d_in[3];
  const float* bhf1   = (const float*)d_in[4];
  const float* wib1   = (const float*)d_in[5];
  const float* whb1   = (const float*)d_in[6];
  const float* bib1   = (const float*)d_in[7];
  const float* bhb1   = (const float*)d_in[8];
  const float* wif2   = (const float*)d_in[9];
  const float* whf2   = (const float*)d_in[10];
  const float* bif2   = (const float*)d_in[11];
  const float* bhf2   = (const float*)d_in[12];
  const float* wib2   = (const float*)d_in[13];
  const float* whb2   = (const float*)d_in[14];
  const float* bib2   = (const float*)d_in[15];
  const float* bhb2   = (const float*)d_in[16];
  const float* w_out  = (const float*)d_in[17];
  const float* b_out  = (const float*)d_in[18];

  char* ws = (char*)d_ws;
  __hip_bfloat16* WXp = (__hip_bfloat16*)(ws + OFF_WXP);
  __hip_bfloat16* WHp = (__hip_bfloat16*)(ws + OFF_WHP);
  float*    B1  = (float*)(ws + OFF_B1);
  __hip_bfloat16* W2B = (__hip_bfloat16*)(ws + OFF_W2B);
  float*    W2I = (float*)(ws + OFF_W2I);
  float*    SE  = (float*)(ws + OFF_SE);
  float*    XG2 = (float*)(ws + OFF_XG2);
  float*    H2O = (float*)(ws + OFF_H2O);
  __hip_bfloat16* XBF = (__hip_bfloat16*)(ws + OFF_XBF);
  float*    XG1 = (float*)(ws + OFF_XG1);

  const bool useBF = (ws_size >= NEED_BF);
  const bool useSPLIT = (ws_size >= NEED_SPLIT);

  prep_kernel<<<(PE4 + 255) / 256, 256, 0, stream>>>(
      wif1, whf1, bif1, bhf1, wib1, whb1, bib1, bhb1,
      wif2, wib2, whf2, whb2, WXp, WHp, B1, W2B, W2I);

  if (useBF)
    xcvt_kernel<<<4096, 256, 0, stream>>>(x, XBF);

  if (useSPLIT) {
    (void)hipFuncSetAttribute((const void*)xg1_gemm,
                              hipFuncAttributeMaxDynamicSharedMemorySize, GA_SMEM);
    xg1_gemm<<<10240, 512, GA_SMEM, stream>>>(XBF, WXp, B1, XG1);
    lstm1_rec<<<256, 640, 0, stream>>>(XG1, WHp, SE);
  } else {
    (void)hipFuncSetAttribute((const void*)(lstm1_kernel<true>),
                              hipFuncAttributeMaxDynamicSharedMemorySize, L1_SMEM);
    (void)hipFuncSetAttribute((const void*)(lstm1_kernel<false>),
                              hipFuncAttributeMaxDynamicSharedMemorySize, L1_SMEM);
    if (useBF)
      lstm1_kernel<true><<<256, 640, L1_SMEM, stream>>>(x, XBF, WXp, WHp, B1, SE);
    else
      lstm1_kernel<false><<<256, 640, L1_SMEM, stream>>>(x, XBF, WXp, WHp, B1, SE);
  }

  xg2_kernel<<<64, 256, 0, stream>>>(SE, W2I, bif2, bhf2, bib2, bhb2, XG2);

  lstm2_kernel<<<2, 640, 0, stream>>>(W2B, XG2, H2O);

  head_kernel<<<4, 256, 0, stream>>>(H2O, w_out, b_out, (float*)d_out);
}

// Round 15
// 1376.254 us; speedup vs baseline: 1.5013x; 1.1698x over previous
//
#include <hip/hip_runtime.h>
#include <hip/hip_bf16.h>
#include <hip/hip_fp16.h>

typedef short bf16x8 __attribute__((ext_vector_type(8)));
typedef float f32x4 __attribute__((ext_vector_type(4)));
typedef unsigned short u16x4 __attribute__((ext_vector_type(4)));
typedef unsigned int uint32;

#define MFMA_B16(a,b,c) __builtin_amdgcn_mfma_f32_16x16x32_bf16(a,b,c,0,0,0)

// ---------------- geometry ----------------
#define NS   1024
#define TLEN 128
#define DD   343
#define HH   150
#define GG   600
#define KX   352
#define XR   360    // LDS row width for x tiles (720B)
#define HR   168
#define KXP  44
#define NP   640    // gate-major: n' = gate*160 + j
#define NG2  640

// ---------------- ws layout (bytes) ----------------
#define OFF_WXP  0u
#define OFF_WHP  901120u
#define OFF_B1   1310720u
#define OFF_W2B  1315840u
#define OFF_W2I  1725440u
#define OFF_SE   3184640u
#define OFF_XG2  4413440u
#define OFF_H2O  9656320u
#define OFF_XBF  10885120u          // bf16 [1024][128][352] = 92274688
#define NEED_BF  103159808ull
#define OFF_XG1  103159808ull       // bf16 [2][CS][128][640], CS adaptive

// prep section boundaries
#define PE0 450560
#define PE1 655360
#define PE2 656640
#define PE3 861440
#define PE4 1226240

__device__ __forceinline__ float rcp_fast(float x) { return __builtin_amdgcn_rcpf(x); }
__device__ __forceinline__ float sigm(float x) { return rcp_fast(1.f + __expf(-x)); }
__device__ __forceinline__ float tanh_fast(float x) { return 1.f - 2.f * rcp_fast(__expf(2.f * x) + 1.f); }

typedef __attribute__((address_space(1))) const void GASV;
typedef __attribute__((address_space(3))) void LASV;
__device__ __forceinline__ void gload_lds16(const void* g, void* l) {
  __builtin_amdgcn_global_load_lds((GASV*)g, (LASV*)l, 16, 0, 0);
}

__device__ __forceinline__ void bar_lds() {
  asm volatile("s_waitcnt lgkmcnt(0)" ::: "memory");
  __builtin_amdgcn_s_barrier();
  asm volatile("" ::: "memory");
}
__device__ __forceinline__ void bar_full() {
  asm volatile("s_waitcnt vmcnt(0) lgkmcnt(0)" ::: "memory");
  __builtin_amdgcn_s_barrier();
  asm volatile("" ::: "memory");
}

__device__ __forceinline__ unsigned short f2bu(float v) {
  __hip_bfloat16 b = __float2bfloat16(v);
  return __builtin_bit_cast(unsigned short, b);
}

// ---------------- prep: pack weights gate-major ----------------
__global__ __launch_bounds__(256) void prep_kernel(
    const float* __restrict__ wif1, const float* __restrict__ whf1,
    const float* __restrict__ bif1, const float* __restrict__ bhf1,
    const float* __restrict__ wib1, const float* __restrict__ whb1,
    const float* __restrict__ bib1, const float* __restrict__ bhb1,
    const float* __restrict__ wif2, const float* __restrict__ wib2,
    const float* __restrict__ whf2, const float* __restrict__ whb2,
    __hip_bfloat16* __restrict__ WXp, __hip_bfloat16* __restrict__ WHp,
    float* __restrict__ B1, __hip_bfloat16* __restrict__ W2B, float* __restrict__ W2I)
{
  int i = blockIdx.x * 256 + threadIdx.x;
  if (i < PE0) {
    int d = i / 225280; int r = i - d * 225280;
    int p = r / 5120;   int r2 = r - p * 5120;
    int n2 = r2 >> 3;   int jj = r2 & 7;
    int k = p * 8 + jj;
    int g = n2 / 160, j = n2 - g * 160;
    const float* w = d ? wib1 : wif1;
    float v = (j < HH && k < DD) ? w[(g * HH + j) * DD + k] : 0.f;
    WXp[i] = __float2bfloat16(v);
  } else if (i < PE1) {
    int ii = i - PE0;
    int d = ii / 102400; int r = ii - d * 102400;
    int p = r / 5120;    int r2 = r - p * 5120;
    int n2 = r2 >> 3;    int jj = r2 & 7;
    int k = p * 8 + jj;
    int g = n2 / 160, j = n2 - g * 160;
    const float* w = d ? whb1 : whf1;
    float v = (j < HH && k < HH) ? w[(g * HH + j) * HH + k] : 0.f;
    WHp[ii] = __float2bfloat16(v);
  } else if (i < PE2) {
    int ii = i - PE1;
    int d = ii / NP; int n2 = ii - d * NP;
    int g = n2 / 160, j = n2 - g * 160;
    float v = 0.f;
    if (j < HH) {
      int n = g * HH + j;
      v = d ? (bib1[n] + bhb1[n]) : (bif1[n] + bhf1[n]);
    }
    B1[ii] = v;
  } else if (i < PE3) {
    int ii = i - PE2;
    int d = ii / 102400; int r = ii - d * 102400;
    int n2 = r / 160;    int k = r - n2 * 160;
    int g = n2 / 160, j = n2 - g * 160;
    const float* w = d ? whb2 : whf2;
    float v = (j < HH && k < HH) ? w[(g * HH + j) * HH + k] : 0.f;
    W2B[ii] = __float2bfloat16(v);
  } else if (i < PE4) {
    int ii = i - PE3;
    int d = ii / 182400; int r = ii - d * 182400;
    int k = r / 608;     int n = r - k * 608;
    const float* w = d ? wib2 : wif2;
    float v = (n < GG) ? w[n * 300 + k] : 0.f;
    W2I[ii] = v;
  }
}

// ---------------- x -> bf16 padded [S][T][352] ----------------
__global__ __launch_bounds__(256) void xcvt_kernel(
    const float* __restrict__ x, __hip_bfloat16* __restrict__ XBF)
{
  const int total4 = NS * TLEN * (KX / 4);
  for (int idx = blockIdx.x * 256 + threadIdx.x; idx < total4; idx += gridDim.x * 256) {
    int row = idx / 88;
    int c4 = (idx - row * 88) * 4;
    const float* src = x + (size_t)row * DD + c4;
    float v0 = 0.f, v1 = 0.f, v2 = 0.f, v3 = 0.f;
    if (c4 + 3 < DD) {
      v0 = __builtin_nontemporal_load(src);
      v1 = __builtin_nontemporal_load(src + 1);
      v2 = __builtin_nontemporal_load(src + 2);
      v3 = __builtin_nontemporal_load(src + 3);
    } else {
      if (c4 < DD)     v0 = src[0];
      if (c4 + 1 < DD) v1 = src[1];
      if (c4 + 2 < DD) v2 = src[2];
    }
    u16x4 o;
    o.x = f2bu(v0); o.y = f2bu(v1); o.z = f2bu(v2); o.w = f2bu(v3);
    u16x4* dst = (u16x4*)((unsigned short*)XBF + (size_t)row * KX + c4);
    __builtin_nontemporal_store(o, dst);
  }
}

// ---------------- layer-1 input GEMM (chunked): XG1 = XBF @ WXp^T + B1 (bf16 out) ----------------
// One block = one sentence x one dir x ALL 640 gates: A (128x352, 90KB) staged
// once via gload_lds; two n-half passes (n=320 each) reuse it. B (450KB/dir)
// stays L2-hot (reuse flux ~1.8MB < 4MB/XCD). Grid = 2*CS.
#define GA_SMEM (128u * 720u)   // 92160

__global__ __launch_bounds__(512) void xg1_gemm(
    const __hip_bfloat16* __restrict__ XBF, const __hip_bfloat16* __restrict__ WXp,
    const float* __restrict__ B1, __hip_bfloat16* __restrict__ XG1,
    int sBase, int CS)
{
  extern __shared__ char smem[];
  __hip_bfloat16* xsA = (__hip_bfloat16*)smem;

  const int bid = blockIdx.x;
  const int dir = bid & 1;
  const int mtl = bid >> 1;            // chunk-local sentence
  const int sg = sBase + mtl;          // global sentence

  const int tid = threadIdx.x;
  const int lane = tid & 63;
  const int wv = tid >> 6;             // 0..7
  const int wr = wv >> 2;              // 0..1 (m-half of 64)
  const int wc = wv & 3;               // 0..3 (n-slice of 80)
  const int c16 = lane & 15;
  const int kgrp = lane >> 4;

  // stage A: 128 rows (t) x 704B
  #pragma unroll
  for (int i = 0; i < 16; ++i) {
    int rid = wv * 16 + i;
    if (lane < 44) {
      const __hip_bfloat16* gp = XBF + ((size_t)sg * TLEN + rid) * KX + lane * 8;
      gload_lds16((const void*)gp, (void*)(smem + rid * 720));
    }
  }
  bar_full();

  const __hip_bfloat16* WXd = WXp + (size_t)dir * KXP * NP * 8;
  __hip_bfloat16* outd = XG1 + ((size_t)dir * CS + mtl) * TLEN * NG2;

  #pragma unroll
  for (int nh = 0; nh < 2; ++nh) {
    const int nbase = nh * 320 + wc * 80;
    f32x4 acc[4][5];
    #pragma unroll
    for (int mi = 0; mi < 4; ++mi)
      #pragma unroll
      for (int nf = 0; nf < 5; ++nf) acc[mi][nf] = (f32x4){0.f, 0.f, 0.f, 0.f};

    for (int kk = 0; kk < 11; ++kk) {
      bf16x8 a[4], b[5];
      #pragma unroll
      for (int mi = 0; mi < 4; ++mi)
        a[mi] = *reinterpret_cast<const bf16x8*>(
            xsA + (wr * 64 + mi * 16 + c16) * XR + kk * 32 + kgrp * 8);
      #pragma unroll
      for (int nf = 0; nf < 5; ++nf)
        b[nf] = *reinterpret_cast<const bf16x8*>(
            WXd + ((size_t)(kk * 4 + kgrp) * NP + nbase + nf * 16 + c16) * 8);
      #pragma unroll
      for (int mi = 0; mi < 4; ++mi)
        #pragma unroll
        for (int nf = 0; nf < 5; ++nf)
          acc[mi][nf] = MFMA_B16(a[mi], b[nf], acc[mi][nf]);
    }

    float bias[5];
    #pragma unroll
    for (int nf = 0; nf < 5; ++nf)
      bias[nf] = B1[dir * NP + nbase + nf * 16 + c16];

    #pragma unroll
    for (int mi = 0; mi < 4; ++mi)
      #pragma unroll
      for (int r = 0; r < 4; ++r) {
        int t = wr * 64 + mi * 16 + kgrp * 4 + r;
        __hip_bfloat16* row = outd + (size_t)t * NG2;
        #pragma unroll
        for (int nf = 0; nf < 5; ++nf)
          row[nbase + nf * 16 + c16] = __float2bfloat16(acc[mi][nf][r] + bias[nf]);
      }
  }
}

// ---------------- layer-1 recurrence (reads bf16 XG1 chunk) ----------------
__global__ __launch_bounds__(640) void lstm1_rec(
    const __hip_bfloat16* __restrict__ XG1, const __hip_bfloat16* __restrict__ WHp,
    float* __restrict__ SE, int sBase, int CS)
{
  __shared__ __hip_bfloat16 hs[16 * HR];

  const int tid = threadIdx.x;
  const int lane = tid & 63;
  const int wv = tid >> 6;
  const int dir = blockIdx.x & 1;
  const int grp = blockIdx.x >> 1;
  const int cls0 = grp * 8;            // chunk-local sentence base
  const int s0g = sBase + cls0;        // global
  const int c16 = lane & 15;
  const int kgrp = lane >> 4;
  const int j = wv * 16 + c16;

  for (int e = tid; e < 16 * HR; e += 640) hs[e] = __float2bfloat16(0.f);

  const __hip_bfloat16* WHd = WHp + (size_t)dir * 20 * NP * 8;
  bf16x8 whr[5][4];
  #pragma unroll
  for (int kh = 0; kh < 5; ++kh)
    #pragma unroll
    for (int g4 = 0; g4 < 4; ++g4) {
      whr[kh][g4] = *reinterpret_cast<const bf16x8*>(
          WHd + ((size_t)(kh * 4 + kgrp) * NP + g4 * 160 + j) * 8);
      asm volatile("" : "+v"(whr[kh][g4]));
    }

  float creg[4] = {0.f, 0.f, 0.f, 0.f};
  float mxr[4] = {-3e38f, -3e38f, -3e38f, -3e38f};

  const __hip_bfloat16* xgd = XG1 + (size_t)dir * CS * TLEN * NG2;
  const int sentb = cls0 + (kgrp & 1) * 4;
  const int par = kgrp >> 1;

  float xq[16], xqN[16];
  #pragma unroll
  for (int g4 = 0; g4 < 4; ++g4)
    #pragma unroll
    for (int r = 0; r < 4; ++r) {
      int tt = dir ? (127 - par) : par;
      xq[g4 * 4 + r] = __bfloat162float(
          xgd[((size_t)(sentb + r) * TLEN + tt) * NG2 + g4 * 160 + j]);
    }
  __syncthreads();

  for (int p = 0; p < 64; ++p) {
    f32x4 acc[4];
    #pragma unroll
    for (int g4 = 0; g4 < 4; ++g4) {
      acc[g4][0] = xq[g4 * 4 + 0]; acc[g4][1] = xq[g4 * 4 + 1];
      acc[g4][2] = xq[g4 * 4 + 2]; acc[g4][3] = xq[g4 * 4 + 3];
    }
    if (p < 63) {
      #pragma unroll
      for (int g4 = 0; g4 < 4; ++g4)
        #pragma unroll
        for (int r = 0; r < 4; ++r) {
          int tl = 2 * (p + 1) + par;
          int tt = dir ? (127 - tl) : tl;
          xqN[g4 * 4 + r] = __bfloat162float(
              xgd[((size_t)(sentb + r) * TLEN + tt) * NG2 + g4 * 160 + j]);
        }
    }
    // MFMA1: rows 0-7 += h_prev_odd * Wh (rows 8-15 see zeros)
    #pragma unroll
    for (int kh = 0; kh < 5; ++kh) {
      bf16x8 ah = *reinterpret_cast<const bf16x8*>(hs + c16 * HR + kh * 32 + kgrp * 8);
      #pragma unroll
      for (int g4 = 0; g4 < 4; ++g4)
        acc[g4] = MFMA_B16(ah, whr[kh][g4], acc[g4]);
    }
    {
      const bool act = (kgrp < 2);
      #pragma unroll
      for (int r = 0; r < 4; ++r) {
        float iv = sigm(acc[0][r]);
        float fv = sigm(acc[1][r]);
        float gv = tanh_fast(acc[2][r]);
        float ov = sigm(acc[3][r]);
        float cin = __shfl_xor(creg[r], 32);
        float cn = fv * cin + iv * gv;
        float h = ov * tanh_fast(cn);
        creg[r] = act ? cn : creg[r];
        mxr[r] = act ? fmaxf(mxr[r], h) : mxr[r];
        if (act) hs[(8 + kgrp * 4 + r) * HR + j] = __float2bfloat16(h);
      }
    }
    bar_lds();
    // MFMA2: rows 8-15 += h_even * Wh
    #pragma unroll
    for (int kh = 0; kh < 5; ++kh) {
      bf16x8 ah = *reinterpret_cast<const bf16x8*>(hs + c16 * HR + kh * 32 + kgrp * 8);
      #pragma unroll
      for (int g4 = 0; g4 < 4; ++g4)
        acc[g4] = MFMA_B16(ah, whr[kh][g4], acc[g4]);
    }
    {
      const bool act = (kgrp >= 2);
      #pragma unroll
      for (int r = 0; r < 4; ++r) {
        float iv = sigm(acc[0][r]);
        float fv = sigm(acc[1][r]);
        float gv = tanh_fast(acc[2][r]);
        float ov = sigm(acc[3][r]);
        float cin = __shfl_xor(creg[r], 32);
        float cn = fv * cin + iv * gv;
        float h = ov * tanh_fast(cn);
        creg[r] = act ? cn : creg[r];
        mxr[r] = act ? fmaxf(mxr[r], h) : mxr[r];
        if (act) {
          int s = (kgrp - 2) * 4 + r;
          hs[s * HR + j] = __float2bfloat16(h);
          hs[(8 + s) * HR + j] = __float2bfloat16(0.f);
        }
      }
    }
    bar_lds();
    #pragma unroll
    for (int q = 0; q < 16; ++q) xq[q] = xqN[q];
  }

  #pragma unroll
  for (int r = 0; r < 4; ++r) {
    float m = fmaxf(mxr[r], __shfl_xor(mxr[r], 32));
    if (kgrp < 2 && j < HH)
      SE[(size_t)(s0g + kgrp * 4 + r) * 300 + dir * HH + j] = m;
  }
}

// ---------------- FALLBACK layer-1 (round-12 fused) ----------------
#define XS_SZ   46080u
#define HS_OFF  (2u * XS_SZ)
#define L1_SMEM (HS_OFF + 5376u)

template<bool BF>
__device__ __forceinline__ void stage_x(char* xsd, const float* __restrict__ x,
                                        const __hip_bfloat16* __restrict__ XBF,
                                        int t0, int dir, int s0, int tid, int lane, int wv)
{
  if constexpr (BF) {
    #pragma unroll
    for (int i = 0; i < 7; ++i) {
      int rid = wv + i * 10;
      if (rid < 64 && lane < 44) {
        int p = rid >> 4, rr = rid & 15;
        int t = t0 + 2 * p + (rr >> 3);
        int s = s0 + (rr & 7);
        int tt = dir ? (127 - t) : t;
        const __hip_bfloat16* gp = XBF + ((size_t)s * TLEN + tt) * KX + lane * 8;
        gload_lds16((const void*)gp, (void*)(xsd + rid * 720));
      }
    }
  } else {
    for (int e = tid; e < 4 * 16 * XR; e += 640) {
      int row16 = e / XR;
      int col = e - row16 * XR;
      int p = row16 >> 4, rr = row16 & 15;
      int t = t0 + 2 * p + (rr >> 3);
      int s = s0 + (rr & 7);
      int tt = dir ? (127 - t) : t;
      float v = (col < DD) ? x[((size_t)s * TLEN + tt) * DD + col] : 0.f;
      ((__hip_bfloat16*)xsd)[e] = __float2bfloat16(v);
    }
  }
}

template<bool BF>
__global__ __launch_bounds__(640)
void lstm1_kernel(
    const float* __restrict__ x, const __hip_bfloat16* __restrict__ XBF,
    const __hip_bfloat16* __restrict__ WXp, const __hip_bfloat16* __restrict__ WHp,
    const float* __restrict__ B1, float* __restrict__ SE)
{
  extern __shared__ char smem[];
  char* xs0 = smem;
  char* xs1 = smem + XS_SZ;
  __hip_bfloat16* hs = (__hip_bfloat16*)(smem + HS_OFF);

  const int tid = threadIdx.x;
  const int lane = tid & 63;
  const int wv = tid >> 6;
  const int dir = blockIdx.x & 1;
  const int s0 = (blockIdx.x >> 1) * 8;
  const int c16 = lane & 15;
  const int kgrp = lane >> 4;
  const int j = wv * 16 + c16;

  for (int e = tid; e < 16 * HR; e += 640) hs[e] = __float2bfloat16(0.f);

  float bias[4];
  #pragma unroll
  for (int g4 = 0; g4 < 4; ++g4) {
    bias[g4] = B1[dir * NP + g4 * 160 + j];
    asm volatile("" : "+v"(bias[g4]));
  }

  const __hip_bfloat16* WXd = WXp + (size_t)dir * KXP * NP * 8;
  const __hip_bfloat16* WHd = WHp + (size_t)dir * 20 * NP * 8;

  bf16x8 whr[5][4];
  #pragma unroll
  for (int kh = 0; kh < 5; ++kh)
    #pragma unroll
    for (int g4 = 0; g4 < 4; ++g4) {
      whr[kh][g4] = *reinterpret_cast<const bf16x8*>(
          WHd + ((size_t)(kh * 4 + kgrp) * NP + g4 * 160 + j) * 8);
      asm volatile("" : "+v"(whr[kh][g4]));
    }

  float creg[4] = {0.f, 0.f, 0.f, 0.f};
  float mxr[4] = {-3e38f, -3e38f, -3e38f, -3e38f};

  stage_x<BF>(xs0, x, XBF, 0, dir, s0, tid, lane, wv);
  bar_full();

  for (int g = 0; g < 16; ++g) {
    char* xsc = (g & 1) ? xs1 : xs0;
    char* xsn = (g & 1) ? xs0 : xs1;
    const __hip_bfloat16* xsb = (const __hip_bfloat16*)xsc;

    f32x4 acc[4][4];
    #pragma unroll
    for (int p = 0; p < 4; ++p)
      #pragma unroll
      for (int g4 = 0; g4 < 4; ++g4) acc[p][g4] = (f32x4){0.f, 0.f, 0.f, 0.f};

    for (int kk = 0; kk < 11; ++kk) {
      bf16x8 a[4], b[4];
      #pragma unroll
      for (int p = 0; p < 4; ++p)
        a[p] = *reinterpret_cast<const bf16x8*>(xsb + (p * 16 + c16) * XR + kk * 32 + kgrp * 8);
      #pragma unroll
      for (int g4 = 0; g4 < 4; ++g4)
        b[g4] = *reinterpret_cast<const bf16x8*>(
            WXd + ((size_t)(kk * 4 + kgrp) * NP + g4 * 160 + j) * 8);
      #pragma unroll
      for (int p = 0; p < 4; ++p)
        #pragma unroll
        for (int g4 = 0; g4 < 4; ++g4)
          acc[p][g4] = MFMA_B16(a[p], b[g4], acc[p][g4]);
    }

    if (g < 15)
      stage_x<BF>(xsn, x, XBF, (g + 1) * 8, dir, s0, tid, lane, wv);

    #pragma unroll
    for (int p = 0; p < 4; ++p) {
      #pragma unroll
      for (int kh = 0; kh < 5; ++kh) {
        bf16x8 ah = *reinterpret_cast<const bf16x8*>(hs + c16 * HR + kh * 32 + kgrp * 8);
        #pragma unroll
        for (int g4 = 0; g4 < 4; ++g4)
          acc[p][g4] = MFMA_B16(ah, whr[kh][g4], acc[p][g4]);
      }
      {
        const bool act = (kgrp < 2);
        #pragma unroll
        for (int r = 0; r < 4; ++r) {
          float iv = sigm(acc[p][0][r] + bias[0]);
          float fv = sigm(acc[p][1][r] + bias[1]);
          float gv = tanh_fast(acc[p][2][r] + bias[2]);
          float ov = sigm(acc[p][3][r] + bias[3]);
          float cin = __shfl_xor(creg[r], 32);
          float cn = fv * cin + iv * gv;
          float h = ov * tanh_fast(cn);
          creg[r] = act ? cn : creg[r];
          mxr[r] = act ? fmaxf(mxr[r], h) : mxr[r];
          if (act) hs[(8 + kgrp * 4 + r) * HR + j] = __float2bfloat16(h);
        }
      }
      bar_lds();
      #pragma unroll
      for (int kh = 0; kh < 5; ++kh) {
        bf16x8 ah = *reinterpret_cast<const bf16x8*>(hs + c16 * HR + kh * 32 + kgrp * 8);
        #pragma unroll
        for (int g4 = 0; g4 < 4; ++g4)
          acc[p][g4] = MFMA_B16(ah, whr[kh][g4], acc[p][g4]);
      }
      {
        const bool act = (kgrp >= 2);
        #pragma unroll
        for (int r = 0; r < 4; ++r) {
          float iv = sigm(acc[p][0][r] + bias[0]);
          float fv = sigm(acc[p][1][r] + bias[1]);
          float gv = tanh_fast(acc[p][2][r] + bias[2]);
          float ov = sigm(acc[p][3][r] + bias[3]);
          float cin = __shfl_xor(creg[r], 32);
          float cn = fv * cin + iv * gv;
          float h = ov * tanh_fast(cn);
          creg[r] = act ? cn : creg[r];
          mxr[r] = act ? fmaxf(mxr[r], h) : mxr[r];
          if (act) {
            int s = (kgrp - 2) * 4 + r;
            hs[s * HR + j] = __float2bfloat16(h);
            hs[(8 + s) * HR + j] = __float2bfloat16(0.f);
          }
        }
      }
      if (p == 3) bar_full(); else bar_lds();
    }
  }

  #pragma unroll
  for (int r = 0; r < 4; ++r) {
    float m = fmaxf(mxr[r], __shfl_xor(mxr[r], 32));
    if (kgrp < 2 && j < HH)
      SE[(size_t)(s0 + kgrp * 4 + r) * 300 + dir * HH + j] = m;
  }
}

// ---------------- layer-2 input projection ----------------
__global__ __launch_bounds__(256, 1) void xg2_kernel(
    const float* __restrict__ SE, const float* __restrict__ W2I,
    const float* __restrict__ bif2, const float* __restrict__ bhf2,
    const float* __restrict__ bib2, const float* __restrict__ bhb2,
    float* __restrict__ XG2)
{
  __shared__ float se[32 * 304];
  const int d = blockIdx.x >> 5, st = blockIdx.x & 31, sb = st * 32;
  const int tid = threadIdx.x;
  for (int e = tid; e < 32 * 300; e += 256) {
    int si = e / 300, k = e - si * 300;
    se[si * 304 + k] = SE[(size_t)(sb + si) * 300 + k];
  }
  __syncthreads();
  for (int pass = 0; pass < 3; ++pass) {
    int n = pass * 256 + tid;
    if (n < GG) {
      int n2 = (n / 150) * 160 + (n % 150);
      float bias = d ? (bib2[n] + bhb2[n]) : (bif2[n] + bhf2[n]);
      float acc[32];
      #pragma unroll
      for (int si = 0; si < 32; ++si) acc[si] = bias;
      const float* wcol = W2I + (size_t)d * 300 * 608 + n;
      for (int k = 0; k < 300; ++k) {
        float wvv = wcol[(size_t)k * 608];
        #pragma unroll
        for (int si = 0; si < 32; ++si) acc[si] += wvv * se[si * 304 + k];
      }
      #pragma unroll
      for (int si = 0; si < 32; ++si)
        XG2[((size_t)d * NS + sb + si) * NG2 + n2] = acc[si];
    }
  }
  for (int e = tid; e < 32 * 40; e += 256) {
    int si = e / 40, q = e - si * 40;
    int g = q / 10, jp = 150 + (q - g * 10);
    XG2[((size_t)d * NS + sb + si) * NG2 + g * 160 + jp] = 0.f;
  }
}

// ---------------- layer-2 recurrence ----------------
__global__ __launch_bounds__(640) void lstm2_kernel(
    const __hip_bfloat16* __restrict__ W2B, const float* __restrict__ XG2,
    float* __restrict__ H2O)
{
  const int dir = blockIdx.x;
  const int tid = threadIdx.x;
  const int lane = tid & 63;
  const int wv = tid >> 6;
  const int c16 = lane & 15;
  const int kg = lane >> 4;
  const int j = wv * 16 + c16;
  __shared__ __align__(16) __hip_bfloat16 hbuf[2][160];

  const f32x4 ZERO4 = {0.f, 0.f, 0.f, 0.f};

  const __hip_bfloat16* Wd = W2B + (size_t)dir * NP * 160;
  bf16x8 wf[5][4];
  #pragma unroll
  for (int kt = 0; kt < 5; ++kt)
    #pragma unroll
    for (int g4 = 0; g4 < 4; ++g4) {
      wf[kt][g4] = *reinterpret_cast<const bf16x8*>(
          Wd + (size_t)(g4 * 160 + j) * 160 + kt * 32 + kg * 8);
      asm volatile("" : "+v"(wf[kt][g4]));
    }

  if (tid < 160) hbuf[0][tid] = __float2bfloat16(0.f);
  __syncthreads();

  float creg = 0.f;
  const float* xg = XG2 + (size_t)dir * NS * NG2;

  float xqC[8], xqN[8];
  #pragma unroll
  for (int q = 0; q < 2; ++q)
    #pragma unroll
    for (int g4 = 0; g4 < 4; ++g4) {
      int ss2 = dir ? (1023 - q) : q;
      xqC[q * 4 + g4] = xg[(size_t)ss2 * NG2 + g4 * 160 + j];
    }

  for (int grp = 0; grp < 512; ++grp) {
    #pragma unroll
    for (int q = 0; q < 2; ++q)
      #pragma unroll
      for (int g4 = 0; g4 < 4; ++g4) {
        int sl = grp * 2 + 2 + q;
        if (sl < 1024) {
          int ss2 = dir ? (1023 - sl) : sl;
          xqN[q * 4 + g4] = xg[(size_t)ss2 * NG2 + g4 * 160 + j];
        } else {
          xqN[q * 4 + g4] = 0.f;
        }
      }
    #pragma unroll
    for (int q = 0; q < 2; ++q) {
      const int step = grp * 2 + q;
      const int ss = dir ? (1023 - step) : step;
      bf16x8 hf[5];
      #pragma unroll
      for (int kt = 0; kt < 5; ++kt)
        hf[kt] = *reinterpret_cast<const bf16x8*>(&hbuf[q][kt * 32 + kg * 8]);
      f32x4 aA[4], aB[4];
      #pragma unroll
      for (int g4 = 0; g4 < 4; ++g4) {
        aA[g4] = MFMA_B16(hf[0], wf[0][g4], ZERO4);
        aB[g4] = MFMA_B16(hf[1], wf[1][g4], ZERO4);
      }
      #pragma unroll
      for (int g4 = 0; g4 < 4; ++g4) {
        aA[g4] = MFMA_B16(hf[2], wf[2][g4], aA[g4]);
        aB[g4] = MFMA_B16(hf[3], wf[3][g4], aB[g4]);
        aA[g4] = MFMA_B16(hf[4], wf[4][g4], aA[g4]);
      }
      float iv = sigm(aA[0][0] + aB[0][0] + xqC[q * 4 + 0]);
      float fv = sigm(aA[1][0] + aB[1][0] + xqC[q * 4 + 1]);
      float gv = tanh_fast(aA[2][0] + aB[2][0] + xqC[q * 4 + 2]);
      float ov = sigm(aA[3][0] + aB[3][0] + xqC[q * 4 + 3]);
      creg = fv * creg + iv * gv;
      float nh = ov * tanh_fast(creg);
      if (kg == 0) {
        hbuf[q ^ 1][j] = __float2bfloat16(nh);
        if (j < HH) H2O[(size_t)ss * 300 + dir * HH + j] = nh;
      }
      bar_lds();
    }
    #pragma unroll
    for (int q = 0; q < 8; ++q) xqC[q] = xqN[q];
  }
}

// ---------------- head ----------------
__global__ __launch_bounds__(256, 1) void head_kernel(
    const float* __restrict__ H2O, const float* __restrict__ w_out,
    const float* __restrict__ b_out, float* __restrict__ out)
{
  int s = blockIdx.x * 256 + threadIdx.x;
  if (s >= NS) return;
  float acc[7];
  #pragma unroll
  for (int c = 0; c < 7; ++c) acc[c] = b_out[c];
  const float* hrow = H2O + (size_t)s * 300;
  for (int k = 0; k < 300; ++k) {
    float hv = hrow[k];
    #pragma unroll
    for (int c = 0; c < 7; ++c) acc[c] += hv * w_out[c * 300 + k];
  }
  float m = acc[0];
  #pragma unroll
  for (int c = 1; c < 7; ++c) m = fmaxf(m, acc[c]);
  float sum = 0.f;
  #pragma unroll
  for (int c = 0; c < 7; ++c) sum += __expf(acc[c] - m);
  float lse = m + __logf(sum);
  #pragma unroll
  for (int c = 0; c < 7; ++c) out[s * 7 + c] = acc[c] - lse;
}

extern "C" void kernel_launch(void* const* d_in, const int* in_sizes, int n_in,
                              void* d_out, int out_size, void* d_ws, size_t ws_size,
                              hipStream_t stream) {
  const float* x      = (const float*)d_in[0];
  const float* wif1   = (const float*)d_in[1];
  const float* whf1   = (const float*)d_in[2];
  const float* bif1   = (const float*)d_in[3];
  const float* bhf1   = (const float*)d_in[4];
  const float* wib1   = (const float*)d_in[5];
  const float* whb1   = (const float*)d_in[6];
  const float* bib1   = (const float*)d_in[7];
  const float* bhb1   = (const float*)d_in[8];
  const float* wif2   = (const float*)d_in[9];
  const float* whf2   = (const float*)d_in[10];
  const float* bif2   = (const float*)d_in[11];
  const float* bhf2   = (const float*)d_in[12];
  const float* wib2   = (const float*)d_in[13];
  const float* whb2   = (const float*)d_in[14];
  const float* bib2   = (const float*)d_in[15];
  const float* bhb2   = (const float*)d_in[16];
  const float* w_out  = (const float*)d_in[17];
  const float* b_out  = (const float*)d_in[18];

  char* ws = (char*)d_ws;
  __hip_bfloat16* WXp = (__hip_bfloat16*)(ws + OFF_WXP);
  __hip_bfloat16* WHp = (__hip_bfloat16*)(ws + OFF_WHP);
  float*    B1  = (float*)(ws + OFF_B1);
  __hip_bfloat16* W2B = (__hip_bfloat16*)(ws + OFF_W2B);
  float*    W2I = (float*)(ws + OFF_W2I);
  float*    SE  = (float*)(ws + OFF_SE);
  float*    XG2 = (float*)(ws + OFF_XG2);
  float*    H2O = (float*)(ws + OFF_H2O);
  __hip_bfloat16* XBF = (__hip_bfloat16*)(ws + OFF_XBF);
  __hip_bfloat16* XG1 = (__hip_bfloat16*)(ws + OFF_XG1);

  const bool useBF = (ws_size >= NEED_BF);

  // adaptive chunk: XG1 chunk bytes = CS * 327680 (bf16 [2][CS][128][640])
  int CS = 0;
  if (useBF && ws_size >= NEED_BF + 128ull * 327680ull) {
    size_t avail = ws_size - NEED_BF;
    CS = 1024;
    while ((size_t)CS * 327680ull > avail) CS >>= 1;
  }

  prep_kernel<<<(PE4 + 255) / 256, 256, 0, stream>>>(
      wif1, whf1, bif1, bhf1, wib1, whb1, bib1, bhb1,
      wif2, wib2, whf2, whb2, WXp, WHp, B1, W2B, W2I);

  if (useBF)
    xcvt_kernel<<<4096, 256, 0, stream>>>(x, XBF);

  if (CS > 0) {
    (void)hipFuncSetAttribute((const void*)xg1_gemm,
                              hipFuncAttributeMaxDynamicSharedMemorySize, GA_SMEM);
    for (int sBase = 0; sBase < NS; sBase += CS) {
      xg1_gemm<<<2 * CS, 512, GA_SMEM, stream>>>(XBF, WXp, B1, XG1, sBase, CS);
      lstm1_rec<<<CS / 4, 640, 0, stream>>>(XG1, WHp, SE, sBase, CS);
    }
  } else {
    (void)hipFuncSetAttribute((const void*)(lstm1_kernel<true>),
                              hipFuncAttributeMaxDynamicSharedMemorySize, L1_SMEM);
    (void)hipFuncSetAttribute((const void*)(lstm1_kernel<false>),
                              hipFuncAttributeMaxDynamicSharedMemorySize, L1_SMEM);
    if (useBF)
      lstm1_kernel<true><<<256, 640, L1_SMEM, stream>>>(x, XBF, WXp, WHp, B1, SE);
    else
      lstm1_kernel<false><<<256, 640, L1_SMEM, stream>>>(x, XBF, WXp, WHp, B1, SE);
  }

  xg2_kernel<<<64, 256, 0, stream>>>(SE, W2I, bif2, bhf2, bib2, bhb2, XG2);

  lstm2_kernel<<<2, 640, 0, stream>>>(W2B, XG2, H2O);

  head_kernel<<<4, 256, 0, stream>>>(H2O, w_out, b_out, (float*)d_out);
}